// Round 11
// baseline (494.190 us; speedup 1.0000x reference)
//
#include <hip/hip_runtime.h>
#include <hip/hip_bf16.h>

using u16 = unsigned short;
using u32 = unsigned int;
typedef short short8 __attribute__((ext_vector_type(8)));
typedef float f32x4 __attribute__((ext_vector_type(4)));

#define B_  2
#define S_  2048
#define E_  768
#define BS_ 4096

#define L2E_ 1.44269504088896f
#define FML2_ 17.3123404906676f   // 12.0 * log2(e) fixed softmax stabilizer

__device__ __forceinline__ u16 f2bf(float f) {
  __hip_bfloat16 h = __float2bfloat16(f);
  return *reinterpret_cast<u16*>(&h);
}

__device__ __forceinline__ u32 pk2(float a, float b) {
  return (u32)f2bf(a) | ((u32)f2bf(b) << 16);
}

// bijective XCD-chunked remap (requires n % 8 == 0): HW assigns consecutive
// blockIdx round-robin to XCDs; this gives each XCD a CONTIGUOUS logical
// range so blocks sharing operand tiles hit the same XCD L2.
__device__ __forceinline__ int xcd_swz(int flat, int n) {
  return (flat & 7) * (n >> 3) + (flat >> 3);
}

// async global->LDS, 16B per lane. LDS dest must be wave-uniform base + lane*16.
__device__ __forceinline__ void gld16(const void* g, void* l) {
  __builtin_amdgcn_global_load_lds(
      (const __attribute__((address_space(1))) u32*)g,
      (__attribute__((address_space(3))) u32*)l, 16, 0, 0);
}

// ---- [128][64] bf16 tile staging with XOR-involution swizzle ----
// stored[row][slot] = src[row][slot ^ (row&7)] (8 slots of 8 u16 = 16B).
// LDS dest is linear (wave-uniform base + lane*16B); source pre-swizzled.
// Conflict-free on both sides (verified: SQ_LDS_BANK_CONFLICT == 0).
__device__ __forceinline__ void stage64(const u16* __restrict__ src, int srcStride,
                                        u16* buf, int w, int lane) {
  const int rl = lane >> 3;          // row offset within 8-row group
  const int cg0 = lane & 7;          // stored 16B slot
#pragma unroll
  for (int it = 0; it < 4; ++it) {
    int r0 = w * 32 + it * 8;
    int row = r0 + rl;
    int cg = cg0 ^ (row & 7);        // pre-swizzled source col-group
    gld16(src + (size_t)row * srcStride + cg * 8, buf + r0 * 64 + lane * 8);
  }
}

// read 8 consecutive bf16 at k-offset kt + quad*8 from row r (undoes the XOR)
__device__ __forceinline__ short8 rdfrag64(const u16* buf, int r, int kt, int quad) {
  int slot = (((kt >> 3) + quad) ^ (r & 7)) & 7;
  return *reinterpret_cast<const short8*>(buf + r * 64 + slot * 8);
}

// one 64-wide K-chunk of 128x128 MFMA from staged tiles
__device__ __forceinline__ void mfma_chunk64(const u16* lA, const u16* lB,
                                             f32x4 (&acc)[4][4],
                                             int w, int l15, int quad) {
#pragma unroll
  for (int kt = 0; kt < 64; kt += 32) {
    short8 af[4], bg[4];
#pragma unroll
    for (int i = 0; i < 4; ++i)
      af[i] = rdfrag64(lA, (w >> 1) * 64 + i * 16 + l15, kt, quad);
#pragma unroll
    for (int j = 0; j < 4; ++j)
      bg[j] = rdfrag64(lB, (w & 1) * 64 + j * 16 + l15, kt, quad);
#pragma unroll
    for (int i = 0; i < 4; ++i)
#pragma unroll
      for (int j = 0; j < 4; ++j)
        acc[i][j] = __builtin_amdgcn_mfma_f32_16x16x32_bf16(af[i], bg[j], acc[i][j], 0, 0, 0);
  }
}

// ---------------- fused preprocessing: conv-x | conv-weights | transposes |
// biases. One launch; block ranges select the task. ----------------
struct PrepP {
  const float* x;  u16* Xb;
  const float* row; const float* cow; u16* Wrc;   // [ro_w;co_w] -> bf16 straight
  const float* tsrc[7]; u16* tdst[7]; int trows[7];
  const float* rqb; const float* rkb; const float* rvb;
  const float* cqb; const float* ckb; const float* cvb;
  const float* rcb; const float* ccb;
  float* bqkv; float* bzero;
};

__global__ __launch_bounds__(256) void prep_k(PrepP p) {
  const int bid = blockIdx.x, tid = threadIdx.x;
  __shared__ float tsh[32][33];
  if (bid < 3072) {                       // x -> Xb bf16 (786432 float4s)
    int i = bid * 256 + tid;
    float4 v = reinterpret_cast<const float4*>(p.x)[i];
    reinterpret_cast<uint2*>(p.Xb)[i] = make_uint2(pk2(v.x, v.y), pk2(v.z, v.w));
  } else if (bid < 4224) {                // [ro_w;co_w] -> Wrc bf16 (294912 f4)
    int i = (bid - 3072) * 256 + tid;
    const float* s = (i < 147456) ? p.row : p.cow;
    int k = (i < 147456) ? i : i - 147456;
    float4 v = reinterpret_cast<const float4*>(s)[k];
    reinterpret_cast<uint2*>(p.Wrc)[i] = make_uint2(pk2(v.x, v.y), pk2(v.z, v.w));
  } else if (bid < 8832) {                // transposes: 6x(24x24) + 1x(48x24)
    int tb = bid - 4224;
    int mi, ty, tx;
    if (tb < 3456) { mi = tb / 576; int r = tb - mi * 576; ty = r / 24; tx = r - ty * 24; }
    else           { int r = tb - 3456; mi = 6; ty = r / 24; tx = r - ty * 24; }
    const float* src = p.tsrc[mi];
    u16* dst = p.tdst[mi];
    const int rows = p.trows[mi];
    const int r0 = ty * 32, c0 = tx * 32;
    const int txx = tid & 31, tyy = tid >> 5;
#pragma unroll
    for (int d = 0; d < 4; ++d) {
      int r = tyy + d * 8;
      tsh[r][txx] = src[(size_t)(r0 + r) * 768 + c0 + txx];
    }
    __syncthreads();
#pragma unroll
    for (int d = 0; d < 4; ++d) {
      int c = tyy + d * 8;
      dst[(size_t)(c0 + c) * rows + r0 + txx] = f2bf(tsh[txx][c]);
    }
  } else {                                // bqkv + bzero (24 blocks)
    int t = (bid - 8832) * 256 + tid;
    if (t < 4608) {
      int seg = t / 768, i = t - seg * 768;
      float v = 0.f;
      if      (seg == 0) v = p.rqb[i] + p.rcb[i];   // cultural bias folds into Q bias
      else if (seg == 1) v = p.rkb[i];
      else if (seg == 2) v = p.rvb[i];
      else if (seg == 3) v = p.cqb[i] + p.ccb[i];
      else if (seg == 4) v = p.ckb[i];
      else               v = p.cvb[i];
      p.bqkv[t] = v;
    } else if (t < 6144) {
      p.bzero[t - 4608] = 0.f;
    }
  }
}

// ============ transposed GEMM body: computes C^T with A[M][K], BT[N][K].
// BK=64. DB=1: double-buffered pipeline (stage t+1 || compute t, 1 barrier
// per chunk). MODE 0: PROJ (bf16), MODE 1: FINAL (fp32), MODE 2: QKVT ============

template<int MODE, int DB>
__device__ __forceinline__ void gemm_body(
    u16* lA, u16* lB, int bx, int by,
    const u16* __restrict__ A, int lda,
    const u16* __restrict__ BT, int ldb,
    const float* __restrict__ bias, int K,
    const u16* __restrict__ A2, int msplit, int bofs,
    void* __restrict__ Cout, int ldc,
    u16* __restrict__ Qr, u16* __restrict__ Kr, u16* __restrict__ Vtr,
    u16* __restrict__ Qc, u16* __restrict__ Kc, u16* __restrict__ Vtc) {
  const int tid = threadIdx.x, w = tid >> 6, lane = tid & 63;
  const int quad = lane >> 4, l15 = lane & 15;
  const int m0 = by * 128, n0 = bx * 128;
  if (msplit && m0 >= msplit) { A = A2 - (size_t)msplit * lda; BT += bofs; }

  const f32x4 z4 = {0.f, 0.f, 0.f, 0.f};
  f32x4 acc[4][4];
#pragma unroll
  for (int i = 0; i < 4; ++i)
#pragma unroll
    for (int j = 0; j < 4; ++j) acc[i][j] = z4;

  if constexpr (DB) {
    const int nt = K >> 6;
    stage64(A + (size_t)m0 * lda, lda, lA, w, lane);
    stage64(BT + (size_t)n0 * ldb, ldb, lB, w, lane);
    __syncthreads();
    int cur = 0;
    for (int t = 0; t < nt; ++t) {
      if (t + 1 < nt) {
        stage64(A + (size_t)m0 * lda + (t + 1) * 64, lda, lA + (cur ^ 1) * (128 * 64), w, lane);
        stage64(BT + (size_t)n0 * ldb + (t + 1) * 64, ldb, lB + (cur ^ 1) * (128 * 64), w, lane);
      }
      mfma_chunk64(lA + cur * (128 * 64), lB + cur * (128 * 64), acc, w, l15, quad);
      __syncthreads();
      cur ^= 1;
    }
  } else {
    for (int kc = 0; kc < K; kc += 64) {
      stage64(A + (size_t)m0 * lda + kc, lda, lA, w, lane);
      stage64(BT + (size_t)n0 * ldb + kc, ldb, lB, w, lane);
      __syncthreads();
      mfma_chunk64(lA, lB, acc, w, l15, quad);
      __syncthreads();
    }
  }

  const int seg = (MODE == 2) ? (m0 / 768) : 0;
#pragma unroll
  for (int i = 0; i < 4; ++i) {
    int f = m0 + (w >> 1) * 64 + i * 16 + quad * 4;   // M-row base (4 consecutive)
    float4 b4 = *reinterpret_cast<const float4*>(bias + f);
#pragma unroll
    for (int j = 0; j < 4; ++j) {
      int t = n0 + (w & 1) * 64 + j * 16 + l15;        // N-col
      float v0 = acc[i][j][0] + b4.x;
      float v1 = acc[i][j][1] + b4.y;
      float v2 = acc[i][j][2] + b4.z;
      float v3 = acc[i][j][3] + b4.w;
      if (MODE == 0) {
        *reinterpret_cast<uint2*>((u16*)Cout + (size_t)t * ldc + f) =
            make_uint2(pk2(v0, v1), pk2(v2, v3));
      } else if (MODE == 1) {
        *reinterpret_cast<float4*>((float*)Cout + (size_t)t * ldc + f) =
            make_float4(v0, v1, v2, v3);
      } else {
        int b = t >> 11, s = t & 2047;
        int fs = f - seg * 768;
        if (seg == 0) {
          int h = fs >> 7, d = fs & 127;
          *reinterpret_cast<uint2*>(Qr + ((size_t)(b * 6 + h) * 2048 + s) * 128 + d) =
              make_uint2(pk2(v0, v1), pk2(v2, v3));
        } else if (seg == 1) {
          int h = fs >> 7, d = fs & 127;
          *reinterpret_cast<uint2*>(Kr + ((size_t)(b * 6 + h) * 2048 + s) * 128 + d) =
              make_uint2(pk2(v0, v1), pk2(v2, v3));
        } else if (seg == 2) {
          int h = fs >> 7, d = fs & 127;
          u16* vp = Vtr + ((size_t)(b * 6 + h) * 128 + d) * 2048 + s;
          vp[0] = f2bf(v0); vp[2048] = f2bf(v1); vp[4096] = f2bf(v2); vp[6144] = f2bf(v3);
        } else if (seg == 3) {
          int h = fs / 384, d = fs - h * 384;
          *reinterpret_cast<uint2*>(Qc + ((size_t)(b * 2 + h) * 2048 + s) * 384 + d) =
              make_uint2(pk2(v0, v1), pk2(v2, v3));
        } else if (seg == 4) {
          int h = fs / 384, d = fs - h * 384;
          *reinterpret_cast<uint2*>(Kc + ((size_t)(b * 2 + h) * 2048 + s) * 384 + d) =
              make_uint2(pk2(v0, v1), pk2(v2, v3));
        } else {
          int h = fs / 384, d = fs - h * 384;
          u16* vp = Vtc + ((size_t)(b * 2 + h) * 384 + d) * 2048 + s;
          vp[0] = f2bf(v0); vp[2048] = f2bf(v1); vp[4096] = f2bf(v2); vp[6144] = f2bf(v3);
        }
      }
    }
  }
}

template<int MODE, int DB>
__global__ __launch_bounds__(256) void gemm_t_k(
    const u16* __restrict__ A, int lda,
    const u16* __restrict__ BT, int ldb,
    const float* __restrict__ bias, int K,
    const u16* __restrict__ A2, int msplit, int bofs,
    void* __restrict__ Cout, int ldc,
    u16* __restrict__ Qr, u16* __restrict__ Kr, u16* __restrict__ Vtr,
    u16* __restrict__ Qc, u16* __restrict__ Kc, u16* __restrict__ Vtc) {
  __shared__ __align__(16) u16 lA[(DB + 1) * 128 * 64];
  __shared__ __align__(16) u16 lB[(DB + 1) * 128 * 64];
  // XCD-chunked remap (grid size must be %8==0)
  const int n = gridDim.x * gridDim.y;
  const int flat = blockIdx.x + gridDim.x * blockIdx.y;
  const int lg = xcd_swz(flat, n);
  const int bx = lg % gridDim.x, by = lg / gridDim.x;
  gemm_body<MODE, DB>(lA, lB, bx, by,
                      A, lda, BT, ldb, bias, K, A2, msplit, bofs, Cout, ldc,
                      Qr, Kr, Vtr, Qc, Kc, Vtc);
}

// ---------------- mega dispatch: QKV gemm + WfT gemm + bfused ----------------
// All three depend only on prep_k; the 264 small blocks ride QKV's execution.
// NOTE: no min-waves launch bound -- round 9's (256,5) pinned the allocator to
// ~96 VGPR and spilled the accumulator (WRITE_SIZE 244 MB of scratch, 170 us).
struct MegaP {
  const u16* WqkvT; const u16* Xb; const float* bqkv;
  u16 *Qr, *Kr, *Vtr, *Qc, *Kc, *Vtc;
  const u16* Wrc; const u16* outwT; const float* bzero; u16* WfT;
  const float *out_b, *ro_b, *co_b; float* bfused;
};

__global__ __launch_bounds__(256) void mega_k(MegaP m) {
  __shared__ __align__(16) u16 lA[128 * 64];
  __shared__ __align__(16) u16 lB[128 * 64];
  const int id = xcd_swz(blockIdx.x, 1416);   // 1416 % 8 == 0
  if (id < 1152) {
    // QKV projection: M=4608 features, N=4096 tokens (grid 32 x 36)
    gemm_body<2, 0>(lA, lB, id & 31, id >> 5,
                    m.WqkvT, 768, m.Xb, 768, m.bqkv, 768,
                    (const u16*)nullptr, 0, 0, (void*)nullptr, 0,
                    m.Qr, m.Kr, m.Vtr, m.Qc, m.Kc, m.Vtc);
  } else if (id < 1224) {
    // WfT[of][if] = sum_m Wrc[if][m] * out_w[m + sel*768][of] (grid 6 x 12)
    const int wf = id - 1152;
    gemm_body<0, 0>(lA, lB, wf % 6, wf / 6,
                    m.Wrc, 768, m.outwT, 1536, m.bzero, 768,
                    m.Wrc + (size_t)768 * 768, 768, 768, (void*)m.WfT, 1536,
                    nullptr, nullptr, nullptr, nullptr, nullptr, nullptr);
  } else {
    // bfused[of] = out_b[of] + sum [ro_b;co_b][m] * outwT[of][m] (192 blocks,
    // one wave per of; 3 independent short8 loads/lane + butterfly)
    float* rcb = reinterpret_cast<float*>(lA);
    const int tid = threadIdx.x, w = tid >> 6, lane = tid & 63;
    for (int i = tid; i < 768; i += 256) {
      rcb[i] = m.ro_b[i];
      rcb[768 + i] = m.co_b[i];
    }
    __syncthreads();
    const int of = (id - 1224) * 4 + w;
    const u16* row = m.outwT + (size_t)of * 1536 + lane * 24;
    const float* rc = rcb + lane * 24;
    float a0 = 0.f, a1 = 0.f, a2 = 0.f, a3 = 0.f;
#pragma unroll
    for (int g = 0; g < 3; ++g) {
      short8 v = *reinterpret_cast<const short8*>(row + g * 8);
      u32 b0 = ((u32)(u16)v[0]) << 16, b1 = ((u32)(u16)v[1]) << 16;
      u32 b2 = ((u32)(u16)v[2]) << 16, b3 = ((u32)(u16)v[3]) << 16;
      u32 b4 = ((u32)(u16)v[4]) << 16, b5 = ((u32)(u16)v[5]) << 16;
      u32 b6 = ((u32)(u16)v[6]) << 16, b7 = ((u32)(u16)v[7]) << 16;
      a0 = fmaf(*reinterpret_cast<float*>(&b0), rc[g * 8 + 0], a0);
      a1 = fmaf(*reinterpret_cast<float*>(&b1), rc[g * 8 + 1], a1);
      a2 = fmaf(*reinterpret_cast<float*>(&b2), rc[g * 8 + 2], a2);
      a3 = fmaf(*reinterpret_cast<float*>(&b3), rc[g * 8 + 3], a3);
      a0 = fmaf(*reinterpret_cast<float*>(&b4), rc[g * 8 + 4], a0);
      a1 = fmaf(*reinterpret_cast<float*>(&b5), rc[g * 8 + 5], a1);
      a2 = fmaf(*reinterpret_cast<float*>(&b6), rc[g * 8 + 6], a2);
      a3 = fmaf(*reinterpret_cast<float*>(&b7), rc[g * 8 + 7], a3);
    }
    float s = (a0 + a1) + (a2 + a3);
    s += __shfl_xor(s, 1);
    s += __shfl_xor(s, 2);
    s += __shfl_xor(s, 4);
    s += __shfl_xor(s, 8);
    s += __shfl_xor(s, 16);
    s += __shfl_xor(s, 32);
    if (lane == 0) m.bfused[of] = s + m.out_b[of];
  }
}

// ---------------- attention g1 (transposed): S^T[k][q] = K·Q^T ----------------
// P stored in BLOCKED layout P[kt][q][128] (kt = k/128). XCD-chunked swizzle:
// each XCD owns contiguous (z,y,x) logical range -> K/Q tiles L2-resident.
__global__ __launch_bounds__(256) void attn_g1_k(
    const u16* __restrict__ Qr, const u16* __restrict__ Kr,
    const u16* __restrict__ Qc, const u16* __restrict__ Kc,
    u16* __restrict__ Pr, u16* __restrict__ Pc, float* __restrict__ Lp,
    const float* __restrict__ am, const float* __restrict__ cmask,
    float sReg, float sCul, int zoff) {
  __shared__ __align__(16) u16 lA[128 * 64];
  __shared__ __align__(16) u16 lB[128 * 64];
  const int tid = threadIdx.x, w = tid >> 6, lane = tid & 63;
  const int quad = lane >> 4, l15 = lane & 15;
  // XCD swizzle (grid sizes are all %8==0)
  const int n = gridDim.x * gridDim.y * gridDim.z;
  const int flat = blockIdx.x + gridDim.x * (blockIdx.y + gridDim.y * blockIdx.z);
  const int lg = xcd_swz(flat, n);
  const int bx = lg % gridDim.x;
  const int tt = lg / gridDim.x;
  const int by = tt % gridDim.y, bz = tt / gridDim.y;
  const int m0 = by * 128, n0 = bx * 128;  // m=key, n=query
  const int gz = zoff + bz;
  const u16 *A, *BT;
  u16* P;
  const float* cm = nullptr;
  float scl;
  int K, b;
  if (gz < 12) {
    A = Kr + (size_t)gz * S_ * 128;
    BT = Qr + (size_t)gz * S_ * 128;
    K = 128;
    P = Pr + (size_t)bz * (size_t)S_ * S_;
    scl = sReg;
    b = gz / 6;
  } else {
    int hc = gz - 12;
    A = Kc + (size_t)hc * S_ * 384;
    BT = Qc + (size_t)hc * S_ * 384;
    K = 384;
    P = Pc + (size_t)hc * (size_t)S_ * S_;
    b = hc >> 1;
    cm = cmask + (size_t)b * S_ * S_;
    scl = sCul;
  }

  const f32x4 z4 = {0.f, 0.f, 0.f, 0.f};
  f32x4 acc[4][4];
#pragma unroll
  for (int i = 0; i < 4; ++i)
#pragma unroll
    for (int j = 0; j < 4; ++j) acc[i][j] = z4;

  for (int kc = 0; kc < K; kc += 64) {
    stage64(A + (size_t)m0 * K + kc, K, lA, w, lane);
    stage64(BT + (size_t)n0 * K + kc, K, lB, w, lane);
    __syncthreads();
    mfma_chunk64(lA, lB, acc, w, l15, quad);
    __syncthreads();
  }

  // epilogue: p = exp2(acc*scl + am[k]*l2e (+ cm[q][k]*l2e) - M)
  // blocked P write: Pb[q][kb&127], dense per block.
  u16* Pb = P + (size_t)(m0 >> 7) * (S_ * 128);
  const float* amb = am + b * S_;
  float lsum[4] = {0.f, 0.f, 0.f, 0.f};
#pragma unroll
  for (int i = 0; i < 4; ++i) {
    int kb = m0 + (w >> 1) * 64 + i * 16 + quad * 4;    // 4 consecutive keys
    int kbl = kb & 127;
    float4 a4 = *reinterpret_cast<const float4*>(amb + kb);
    float pre0 = fmaf(a4.x, L2E_, -FML2_);
    float pre1 = fmaf(a4.y, L2E_, -FML2_);
    float pre2 = fmaf(a4.z, L2E_, -FML2_);
    float pre3 = fmaf(a4.w, L2E_, -FML2_);
#pragma unroll
    for (int j = 0; j < 4; ++j) {
      int q = n0 + (w & 1) * 64 + j * 16 + l15;
      float c0 = pre0, c1 = pre1, c2 = pre2, c3 = pre3;
      if (cm) {
        float4 cmv = *reinterpret_cast<const float4*>(cm + (size_t)q * S_ + kb);
        c0 = fmaf(cmv.x, L2E_, c0);
        c1 = fmaf(cmv.y, L2E_, c1);
        c2 = fmaf(cmv.z, L2E_, c2);
        c3 = fmaf(cmv.w, L2E_, c3);
      }
      float p0 = exp2f(fmaf(acc[i][j][0], scl, c0));
      float p1 = exp2f(fmaf(acc[i][j][1], scl, c1));
      float p2 = exp2f(fmaf(acc[i][j][2], scl, c2));
      float p3 = exp2f(fmaf(acc[i][j][3], scl, c3));
      lsum[j] += (p0 + p1) + (p2 + p3);
      *reinterpret_cast<uint2*>(Pb + (size_t)q * 128 + kbl) =
          make_uint2(pk2(p0, p1), pk2(p2, p3));
    }
  }
#pragma unroll
  for (int j = 0; j < 4; ++j) {
    float s = lsum[j];
    s += __shfl_xor(s, 16);
    s += __shfl_xor(s, 32);
    if (lane < 16)
      Lp[(size_t)gz * (32 * S_) + ((size_t)((m0 >> 7) * 2 + (w >> 1))) * S_ +
         n0 + (w & 1) * 64 + j * 16 + lane] = s;
  }
}

// ---------------- attention g2 (transposed): O^T[d][q] = Vt·P^T ----------------
// P read from blocked layout [kt][q][128]; double-buffered 2-phase pipeline.
// XCD-chunked swizzle: each XCD owns ~2 head-configs -> Vt L2-resident.
__global__ __launch_bounds__(256) void attn_g2_k(
    const u16* __restrict__ Pr, const u16* __restrict__ Pc,
    const u16* __restrict__ Vtr, const u16* __restrict__ Vtc,
    const float* __restrict__ Lp, u16* __restrict__ AO, int zoff) {
  const int n = gridDim.x * gridDim.y * gridDim.z;
  const int flat = blockIdx.x + gridDim.x * (blockIdx.y + gridDim.y * blockIdx.z);
  const int lg = xcd_swz(flat, n);
  const int bx = lg % gridDim.x;
  const int tt = lg / gridDim.x;
  const int by = tt % gridDim.y, bz = tt / gridDim.y;
  const int gz = zoff + bz;
  const int m0 = by * 128, n0 = bx * 128;  // m=feat, n=query
  const u16 *A, *BT;
  int b, colbase;
  if (gz < 12) {
    if (by) return;  // M = 128
    A = Vtr + (size_t)gz * 128 * S_;
    BT = Pr + (size_t)bz * (size_t)S_ * S_;
    b = gz / 6;
    colbase = (gz % 6) * 128;
  } else {
    int hc = gz - 12;
    A = Vtc + (size_t)hc * 384 * S_;
    BT = Pc + (size_t)hc * (size_t)S_ * S_;
    b = hc >> 1;
    colbase = 768 + (hc & 1) * 384;
  }
  __shared__ __align__(16) u16 lA[2][128 * 64];
  __shared__ __align__(16) u16 lB[2][128 * 64];
  __shared__ float lL[128];
  const int tid = threadIdx.x, w = tid >> 6, lane = tid & 63;
  const int quad = lane >> 4, l15 = lane & 15;

  if (tid < 128) {
    const float* lp = Lp + (size_t)gz * (32 * S_) + (n0 + tid);
    float s = 0.f;
#pragma unroll
    for (int g = 0; g < 32; ++g) s += lp[(size_t)g * S_];
    lL[tid] = 1.f / s;
  }

  const f32x4 z4 = {0.f, 0.f, 0.f, 0.f};
  f32x4 acc[4][4];
#pragma unroll
  for (int i = 0; i < 4; ++i)
#pragma unroll
    for (int j = 0; j < 4; ++j) acc[i][j] = z4;

  // blocked-P source for chunk starting at kc
  auto psrc = [&](int kc) {
    return BT + (size_t)(kc >> 7) * (S_ * 128) + (kc & 64) + (size_t)n0 * 128;
  };

  stage64(A + (size_t)m0 * S_, S_, lA[0], w, lane);
  stage64(psrc(0), 128, lB[0], w, lane);
  __syncthreads();
  int cur = 0;
  for (int t = 0; t < 32; ++t) {
    if (t < 31) {
      int kn = (t + 1) * 64;
      stage64(A + (size_t)m0 * S_ + kn, S_, lA[cur ^ 1], w, lane);
      stage64(psrc(kn), 128, lB[cur ^ 1], w, lane);
    }
    mfma_chunk64(lA[cur], lB[cur], acc, w, l15, quad);
    __syncthreads();
    cur ^= 1;
  }

  float invl[4];
#pragma unroll
  for (int j = 0; j < 4; ++j) invl[j] = lL[(w & 1) * 64 + j * 16 + l15];
#pragma unroll
  for (int i = 0; i < 4; ++i) {
    int feat = colbase + m0 + (w >> 1) * 64 + i * 16 + quad * 4;
#pragma unroll
    for (int j = 0; j < 4; ++j) {
      int q = n0 + (w & 1) * 64 + j * 16 + l15;
      float v0 = acc[i][j][0] * invl[j];
      float v1 = acc[i][j][1] * invl[j];
      float v2 = acc[i][j][2] * invl[j];
      float v3 = acc[i][j][3] * invl[j];
      *reinterpret_cast<uint2*>(AO + ((size_t)(b * S_ + q)) * 1536 + feat) =
          make_uint2(pk2(v0, v1), pk2(v2, v3));
    }
  }
}

// ---------------- launcher ----------------

extern "C" void kernel_launch(void* const* d_in, const int* in_sizes, int n_in,
                              void* d_out, int out_size, void* d_ws, size_t ws_size,
                              hipStream_t stream) {
  const float* x     = (const float*)d_in[0];
  const float* cmask = (const float*)d_in[1];
  const float* amask = (const float*)d_in[2];
  const float* W[8]  = { (const float*)d_in[3], (const float*)d_in[4], (const float*)d_in[5],
                         (const float*)d_in[6], (const float*)d_in[7], (const float*)d_in[8],
                         (const float*)d_in[9], (const float*)d_in[10] };
  const float* rq_b = (const float*)d_in[11];
  const float* rk_b = (const float*)d_in[12];
  const float* rv_b = (const float*)d_in[13];
  const float* ro_b = (const float*)d_in[14];
  const float* cq_b = (const float*)d_in[15];
  const float* ck_b = (const float*)d_in[16];
  const float* cv_b = (const float*)d_in[17];
  const float* co_b = (const float*)d_in[18];
  const float* r_cb = (const float*)d_in[19];
  const float* c_cb = (const float*)d_in[20];
  const float* out_w = (const float*)d_in[21];
  const float* out_b = (const float*)d_in[22];

  char* p = (char*)d_ws;
  auto carve = [&](size_t bytes) -> void* {
    void* r = (void*)p;
    p += (bytes + 255) & ~(size_t)255;
    return r;
  };
  u16* Xb    = (u16*)carve((size_t)BS_ * E_ * 2);       // dead after QKV gemm
  u16* WqkvT = (u16*)carve((size_t)4608 * 768 * 2);     // dead after QKV gemm
  u16* outwT = (u16*)carve((size_t)768 * 1536 * 2);
  u16* Wrc   = (u16*)carve((size_t)1536 * 768 * 2);     // [ro_w;co_w] bf16 straight
  u16* WfT   = (u16*)carve((size_t)768 * 1536 * 2);     // fused proj weight
  float* bqkv   = (float*)carve(4608 * 4);
  float* bzero  = (float*)carve(1536 * 4);
  float* bfused = (float*)carve(768 * 4);
  u16* Qr  = (u16*)carve((size_t)B_ * 6 * S_ * 128 * 2);
  u16* Kr  = (u16*)carve((size_t)B_ * 6 * S_ * 128 * 2);
  u16* Vtr = (u16*)carve((size_t)B_ * 6 * S_ * 128 * 2);
  u16* Qc  = (u16*)carve((size_t)B_ * 2 * S_ * 384 * 2);
  u16* Kc  = (u16*)carve((size_t)B_ * 2 * S_ * 384 * 2);
  u16* Vtc = (u16*)carve((size_t)B_ * 2 * S_ * 384 * 2);
  u16* AO  = (u16*)carve((size_t)BS_ * 1536 * 2);

  // Lp aliases dead Xb region (4.2 MB <= 6.3 MB).
  float* Lp = (float*)Xb;
  u16* Pcul = (u16*)carve((size_t)4 * S_ * S_ * 2);     // 33.6 MB
  size_t used = (size_t)(p - (char*)d_ws);
  size_t rem = (ws_size > used) ? (ws_size - used) : 0;
  int RCH;                                              // regular heads per chunk
  if      (rem >= (size_t)12 * S_ * S_ * 2 + 4096) RCH = 12;
  else if (rem >= (size_t)4  * S_ * S_ * 2 + 4096) RCH = 4;
  else                                             RCH = 2;
  u16* Preg = (u16*)carve((size_t)RCH * S_ * S_ * 2);

  const float sReg = 0.08838834764831845f * L2E_;
  const float sCul = 0.05103103630798288f * L2E_;

  // ---- single preprocessing launch ----
  PrepP pp;
  pp.x = x; pp.Xb = Xb;
  pp.row = W[3]; pp.cow = W[7]; pp.Wrc = Wrc;
  const int wsel[6] = {0, 1, 2, 4, 5, 6};  // rq rk rv cq ck cv
  for (int i = 0; i < 6; ++i) {
    pp.tsrc[i] = W[wsel[i]];
    pp.tdst[i] = WqkvT + (size_t)i * 768 * 768;
    pp.trows[i] = 768;
  }
  pp.tsrc[6] = out_w; pp.tdst[6] = outwT; pp.trows[6] = 1536;
  pp.rqb = rq_b; pp.rkb = rk_b; pp.rvb = rv_b;
  pp.cqb = cq_b; pp.ckb = ck_b; pp.cvb = cv_b;
  pp.rcb = r_cb; pp.ccb = c_cb;
  pp.bqkv = bqkv; pp.bzero = bzero;
  prep_k<<<dim3(8856), 256, 0, stream>>>(pp);

  // ---- mega dispatch: QKV (1152) + WfT (72) + bfused (192) ----
  MegaP mp;
  mp.WqkvT = WqkvT; mp.Xb = Xb; mp.bqkv = bqkv;
  mp.Qr = Qr; mp.Kr = Kr; mp.Vtr = Vtr; mp.Qc = Qc; mp.Kc = Kc; mp.Vtc = Vtc;
  mp.Wrc = Wrc; mp.outwT = outwT; mp.bzero = bzero; mp.WfT = WfT;
  mp.out_b = out_b; mp.ro_b = ro_b; mp.co_b = co_b; mp.bfused = bfused;
  mega_k<<<dim3(1416), 256, 0, stream>>>(mp);

  if (RCH == 12) {
    attn_g1_k<<<dim3(16, 16, 16), 256, 0, stream>>>(
        Qr, Kr, Qc, Kc, Preg, Pcul, Lp, amask, cmask, sReg, sCul, 0);
    attn_g2_k<<<dim3(16, 3, 16), 256, 0, stream>>>(
        Preg, Pcul, Vtr, Vtc, Lp, AO, 0);
  } else {
    attn_g1_k<<<dim3(16, 16, 4), 256, 0, stream>>>(
        Qr, Kr, Qc, Kc, Preg, Pcul, Lp, amask, cmask, sReg, sCul, 12);
    attn_g2_k<<<dim3(16, 3, 4), 256, 0, stream>>>(
        Preg, Pcul, Vtr, Vtc, Lp, AO, 12);
    for (int c = 0; c < 12; c += RCH) {
      attn_g1_k<<<dim3(16, 16, RCH), 256, 0, stream>>>(
          Qr, Kr, Qc, Kc, Preg, Pcul, Lp, amask, cmask, sReg, sCul, c);
      attn_g2_k<<<dim3(16, 1, RCH), 256, 0, stream>>>(
          Preg, Pcul, Vtr, Vtc, Lp, AO, c);
    }
  }

  // final fused projection: M=768 out-features, N=4096 tokens, K=1536
  gemm_t_k<1, 1><<<dim3(32, 6), 256, 0, stream>>>(
      WfT, 1536, AO, 1536, bfused, 1536,
      (const u16*)nullptr, 0, 0, d_out, 768,
      nullptr, nullptr, nullptr, nullptr, nullptr, nullptr);
}

// Round 12
// 359.492 us; speedup vs baseline: 1.3747x; 1.3747x over previous
//
#include <hip/hip_runtime.h>
#include <hip/hip_bf16.h>

using u16 = unsigned short;
using u32 = unsigned int;
typedef short short8 __attribute__((ext_vector_type(8)));
typedef float f32x4 __attribute__((ext_vector_type(4)));

#define B_  2
#define S_  2048
#define E_  768
#define BS_ 4096

#define L2E_ 1.44269504088896f
#define FML2_ 17.3123404906676f   // 12.0 * log2(e) fixed softmax stabilizer

__device__ __forceinline__ u16 f2bf(float f) {
  __hip_bfloat16 h = __float2bfloat16(f);
  return *reinterpret_cast<u16*>(&h);
}

__device__ __forceinline__ u32 pk2(float a, float b) {
  return (u32)f2bf(a) | ((u32)f2bf(b) << 16);
}

// async global->LDS, 16B per lane. LDS dest must be wave-uniform base + lane*16.
__device__ __forceinline__ void gld16(const void* g, void* l) {
  __builtin_amdgcn_global_load_lds(
      (const __attribute__((address_space(1))) u32*)g,
      (__attribute__((address_space(3))) u32*)l, 16, 0, 0);
}

// ---- [128][64] bf16 tile staging with XOR-involution swizzle ----
// stored[row][slot] = src[row][slot ^ (row&7)] (8 slots of 8 u16 = 16B).
// LDS dest is linear (wave-uniform base + lane*16B); source pre-swizzled.
// Conflict-free on both sides (verified: SQ_LDS_BANK_CONFLICT == 0).
// NOTE (r11): do NOT add XCD-chunked blockIdx swizzles to these kernels --
// the z-dim work is heterogeneous (cultural heads 3x regular); chunked
// mapping concentrates cultural work on 2/8 XCDs (occupancy 20->10.7%,
// BW 2.5->1.27 TB/s, +132 us). Default round-robin load-balances.
__device__ __forceinline__ void stage64(const u16* __restrict__ src, int srcStride,
                                        u16* buf, int w, int lane) {
  const int rl = lane >> 3;          // row offset within 8-row group
  const int cg0 = lane & 7;          // stored 16B slot
#pragma unroll
  for (int it = 0; it < 4; ++it) {
    int r0 = w * 32 + it * 8;
    int row = r0 + rl;
    int cg = cg0 ^ (row & 7);        // pre-swizzled source col-group
    gld16(src + (size_t)row * srcStride + cg * 8, buf + r0 * 64 + lane * 8);
  }
}

// read 8 consecutive bf16 at k-offset kt + quad*8 from row r (undoes the XOR)
__device__ __forceinline__ short8 rdfrag64(const u16* buf, int r, int kt, int quad) {
  int slot = (((kt >> 3) + quad) ^ (r & 7)) & 7;
  return *reinterpret_cast<const short8*>(buf + r * 64 + slot * 8);
}

// one 64-wide K-chunk of 128x128 MFMA from staged tiles
__device__ __forceinline__ void mfma_chunk64(const u16* lA, const u16* lB,
                                             f32x4 (&acc)[4][4],
                                             int w, int l15, int quad) {
#pragma unroll
  for (int kt = 0; kt < 64; kt += 32) {
    short8 af[4], bg[4];
#pragma unroll
    for (int i = 0; i < 4; ++i)
      af[i] = rdfrag64(lA, (w >> 1) * 64 + i * 16 + l15, kt, quad);
#pragma unroll
    for (int j = 0; j < 4; ++j)
      bg[j] = rdfrag64(lB, (w & 1) * 64 + j * 16 + l15, kt, quad);
#pragma unroll
    for (int i = 0; i < 4; ++i)
#pragma unroll
      for (int j = 0; j < 4; ++j)
        acc[i][j] = __builtin_amdgcn_mfma_f32_16x16x32_bf16(af[i], bg[j], acc[i][j], 0, 0, 0);
  }
}

// ---------------- fused preprocessing: conv-x | conv-weights | transposes |
// biases. One launch; block ranges select the task. ----------------
struct PrepP {
  const float* x;  u16* Xb;
  const float* row; const float* cow; u16* Wrc;   // [ro_w;co_w] -> bf16 straight
  const float* tsrc[7]; u16* tdst[7]; int trows[7];
  const float* rqb; const float* rkb; const float* rvb;
  const float* cqb; const float* ckb; const float* cvb;
  const float* rcb; const float* ccb;
  float* bqkv; float* bzero;
};

__global__ __launch_bounds__(256) void prep_k(PrepP p) {
  const int bid = blockIdx.x, tid = threadIdx.x;
  __shared__ float tsh[32][33];
  if (bid < 3072) {                       // x -> Xb bf16 (786432 float4s)
    int i = bid * 256 + tid;
    float4 v = reinterpret_cast<const float4*>(p.x)[i];
    reinterpret_cast<uint2*>(p.Xb)[i] = make_uint2(pk2(v.x, v.y), pk2(v.z, v.w));
  } else if (bid < 4224) {                // [ro_w;co_w] -> Wrc bf16 (294912 f4)
    int i = (bid - 3072) * 256 + tid;
    const float* s = (i < 147456) ? p.row : p.cow;
    int k = (i < 147456) ? i : i - 147456;
    float4 v = reinterpret_cast<const float4*>(s)[k];
    reinterpret_cast<uint2*>(p.Wrc)[i] = make_uint2(pk2(v.x, v.y), pk2(v.z, v.w));
  } else if (bid < 8832) {                // transposes: 6x(24x24) + 1x(48x24)
    int tb = bid - 4224;
    int mi, ty, tx;
    if (tb < 3456) { mi = tb / 576; int r = tb - mi * 576; ty = r / 24; tx = r - ty * 24; }
    else           { int r = tb - 3456; mi = 6; ty = r / 24; tx = r - ty * 24; }
    const float* src = p.tsrc[mi];
    u16* dst = p.tdst[mi];
    const int rows = p.trows[mi];
    const int r0 = ty * 32, c0 = tx * 32;
    const int txx = tid & 31, tyy = tid >> 5;
#pragma unroll
    for (int d = 0; d < 4; ++d) {
      int r = tyy + d * 8;
      tsh[r][txx] = src[(size_t)(r0 + r) * 768 + c0 + txx];
    }
    __syncthreads();
#pragma unroll
    for (int d = 0; d < 4; ++d) {
      int c = tyy + d * 8;
      dst[(size_t)(c0 + c) * rows + r0 + txx] = f2bf(tsh[txx][c]);
    }
  } else {                                // bqkv + bzero (24 blocks)
    int t = (bid - 8832) * 256 + tid;
    if (t < 4608) {
      int seg = t / 768, i = t - seg * 768;
      float v = 0.f;
      if      (seg == 0) v = p.rqb[i] + p.rcb[i];   // cultural bias folds into Q bias
      else if (seg == 1) v = p.rkb[i];
      else if (seg == 2) v = p.rvb[i];
      else if (seg == 3) v = p.cqb[i] + p.ccb[i];
      else if (seg == 4) v = p.ckb[i];
      else               v = p.cvb[i];
      p.bqkv[t] = v;
    } else if (t < 6144) {
      p.bzero[t - 4608] = 0.f;
    }
  }
}

// ============ transposed GEMM body: computes C^T with A[M][K], BT[N][K].
// BK=64. DB=1: double-buffered pipeline (stage t+1 || compute t, 1 barrier
// per chunk). MODE 0: PROJ (bf16), MODE 1: FINAL (fp32), MODE 2: QKVT ============

template<int MODE, int DB>
__device__ __forceinline__ void gemm_body(
    u16* lA, u16* lB, int bx, int by,
    const u16* __restrict__ A, int lda,
    const u16* __restrict__ BT, int ldb,
    const float* __restrict__ bias, int K,
    const u16* __restrict__ A2, int msplit, int bofs,
    void* __restrict__ Cout, int ldc,
    u16* __restrict__ Qr, u16* __restrict__ Kr, u16* __restrict__ Vtr,
    u16* __restrict__ Qc, u16* __restrict__ Kc, u16* __restrict__ Vtc) {
  const int tid = threadIdx.x, w = tid >> 6, lane = tid & 63;
  const int quad = lane >> 4, l15 = lane & 15;
  const int m0 = by * 128, n0 = bx * 128;
  if (msplit && m0 >= msplit) { A = A2 - (size_t)msplit * lda; BT += bofs; }

  const f32x4 z4 = {0.f, 0.f, 0.f, 0.f};
  f32x4 acc[4][4];
#pragma unroll
  for (int i = 0; i < 4; ++i)
#pragma unroll
    for (int j = 0; j < 4; ++j) acc[i][j] = z4;

  if constexpr (DB) {
    const int nt = K >> 6;
    stage64(A + (size_t)m0 * lda, lda, lA, w, lane);
    stage64(BT + (size_t)n0 * ldb, ldb, lB, w, lane);
    __syncthreads();
    int cur = 0;
    for (int t = 0; t < nt; ++t) {
      if (t + 1 < nt) {
        stage64(A + (size_t)m0 * lda + (t + 1) * 64, lda, lA + (cur ^ 1) * (128 * 64), w, lane);
        stage64(BT + (size_t)n0 * ldb + (t + 1) * 64, ldb, lB + (cur ^ 1) * (128 * 64), w, lane);
      }
      mfma_chunk64(lA + cur * (128 * 64), lB + cur * (128 * 64), acc, w, l15, quad);
      __syncthreads();
      cur ^= 1;
    }
  } else {
    for (int kc = 0; kc < K; kc += 64) {
      stage64(A + (size_t)m0 * lda + kc, lda, lA, w, lane);
      stage64(BT + (size_t)n0 * ldb + kc, ldb, lB, w, lane);
      __syncthreads();
      mfma_chunk64(lA, lB, acc, w, l15, quad);
      __syncthreads();
    }
  }

  const int seg = (MODE == 2) ? (m0 / 768) : 0;
#pragma unroll
  for (int i = 0; i < 4; ++i) {
    int f = m0 + (w >> 1) * 64 + i * 16 + quad * 4;   // M-row base (4 consecutive)
    float4 b4 = *reinterpret_cast<const float4*>(bias + f);
#pragma unroll
    for (int j = 0; j < 4; ++j) {
      int t = n0 + (w & 1) * 64 + j * 16 + l15;        // N-col
      float v0 = acc[i][j][0] + b4.x;
      float v1 = acc[i][j][1] + b4.y;
      float v2 = acc[i][j][2] + b4.z;
      float v3 = acc[i][j][3] + b4.w;
      if (MODE == 0) {
        *reinterpret_cast<uint2*>((u16*)Cout + (size_t)t * ldc + f) =
            make_uint2(pk2(v0, v1), pk2(v2, v3));
      } else if (MODE == 1) {
        *reinterpret_cast<float4*>((float*)Cout + (size_t)t * ldc + f) =
            make_float4(v0, v1, v2, v3);
      } else {
        int b = t >> 11, s = t & 2047;
        int fs = f - seg * 768;
        if (seg == 0) {
          int h = fs >> 7, d = fs & 127;
          *reinterpret_cast<uint2*>(Qr + ((size_t)(b * 6 + h) * 2048 + s) * 128 + d) =
              make_uint2(pk2(v0, v1), pk2(v2, v3));
        } else if (seg == 1) {
          int h = fs >> 7, d = fs & 127;
          *reinterpret_cast<uint2*>(Kr + ((size_t)(b * 6 + h) * 2048 + s) * 128 + d) =
              make_uint2(pk2(v0, v1), pk2(v2, v3));
        } else if (seg == 2) {
          int h = fs >> 7, d = fs & 127;
          u16* vp = Vtr + ((size_t)(b * 6 + h) * 128 + d) * 2048 + s;
          vp[0] = f2bf(v0); vp[2048] = f2bf(v1); vp[4096] = f2bf(v2); vp[6144] = f2bf(v3);
        } else if (seg == 3) {
          int h = fs / 384, d = fs - h * 384;
          *reinterpret_cast<uint2*>(Qc + ((size_t)(b * 2 + h) * 2048 + s) * 384 + d) =
              make_uint2(pk2(v0, v1), pk2(v2, v3));
        } else if (seg == 4) {
          int h = fs / 384, d = fs - h * 384;
          *reinterpret_cast<uint2*>(Kc + ((size_t)(b * 2 + h) * 2048 + s) * 384 + d) =
              make_uint2(pk2(v0, v1), pk2(v2, v3));
        } else {
          int h = fs / 384, d = fs - h * 384;
          u16* vp = Vtc + ((size_t)(b * 2 + h) * 384 + d) * 2048 + s;
          vp[0] = f2bf(v0); vp[2048] = f2bf(v1); vp[4096] = f2bf(v2); vp[6144] = f2bf(v3);
        }
      }
    }
  }
}

template<int MODE, int DB>
__global__ __launch_bounds__(256) void gemm_t_k(
    const u16* __restrict__ A, int lda,
    const u16* __restrict__ BT, int ldb,
    const float* __restrict__ bias, int K,
    const u16* __restrict__ A2, int msplit, int bofs,
    void* __restrict__ Cout, int ldc,
    u16* __restrict__ Qr, u16* __restrict__ Kr, u16* __restrict__ Vtr,
    u16* __restrict__ Qc, u16* __restrict__ Kc, u16* __restrict__ Vtc) {
  __shared__ __align__(16) u16 lA[(DB + 1) * 128 * 64];
  __shared__ __align__(16) u16 lB[(DB + 1) * 128 * 64];
  gemm_body<MODE, DB>(lA, lB, blockIdx.x, blockIdx.y,
                      A, lda, BT, ldb, bias, K, A2, msplit, bofs, Cout, ldc,
                      Qr, Kr, Vtr, Qc, Kc, Vtc);
}

// ---------------- mega dispatch: QKV gemm + WfT gemm + bfused ----------------
// All three depend only on prep_k; the 264 small blocks ride QKV's execution.
// NOTE: no min-waves launch bound -- round 9's (256,5) pinned the allocator to
// ~96 VGPR and spilled the accumulator (WRITE_SIZE 244 MB of scratch, 170 us).
struct MegaP {
  const u16* WqkvT; const u16* Xb; const float* bqkv;
  u16 *Qr, *Kr, *Vtr, *Qc, *Kc, *Vtc;
  const u16* Wrc; const u16* outwT; const float* bzero; u16* WfT;
  const float *out_b, *ro_b, *co_b; float* bfused;
};

__global__ __launch_bounds__(256) void mega_k(MegaP m) {
  __shared__ __align__(16) u16 lA[128 * 64];
  __shared__ __align__(16) u16 lB[128 * 64];
  const int id = blockIdx.x;
  if (id < 1152) {
    // QKV projection: M=4608 features, N=4096 tokens (grid 32 x 36)
    gemm_body<2, 0>(lA, lB, id & 31, id >> 5,
                    m.WqkvT, 768, m.Xb, 768, m.bqkv, 768,
                    (const u16*)nullptr, 0, 0, (void*)nullptr, 0,
                    m.Qr, m.Kr, m.Vtr, m.Qc, m.Kc, m.Vtc);
  } else if (id < 1224) {
    // WfT[of][if] = sum_m Wrc[if][m] * out_w[m + sel*768][of] (grid 6 x 12)
    const int wf = id - 1152;
    gemm_body<0, 0>(lA, lB, wf % 6, wf / 6,
                    m.Wrc, 768, m.outwT, 1536, m.bzero, 768,
                    m.Wrc + (size_t)768 * 768, 768, 768, (void*)m.WfT, 1536,
                    nullptr, nullptr, nullptr, nullptr, nullptr, nullptr);
  } else {
    // bfused[of] = out_b[of] + sum [ro_b;co_b][m] * outwT[of][m] (192 blocks,
    // one wave per of; 3 independent short8 loads/lane + butterfly)
    float* rcb = reinterpret_cast<float*>(lA);
    const int tid = threadIdx.x, w = tid >> 6, lane = tid & 63;
    for (int i = tid; i < 768; i += 256) {
      rcb[i] = m.ro_b[i];
      rcb[768 + i] = m.co_b[i];
    }
    __syncthreads();
    const int of = (id - 1224) * 4 + w;
    const u16* row = m.outwT + (size_t)of * 1536 + lane * 24;
    const float* rc = rcb + lane * 24;
    float a0 = 0.f, a1 = 0.f, a2 = 0.f, a3 = 0.f;
#pragma unroll
    for (int g = 0; g < 3; ++g) {
      short8 v = *reinterpret_cast<const short8*>(row + g * 8);
      u32 b0 = ((u32)(u16)v[0]) << 16, b1 = ((u32)(u16)v[1]) << 16;
      u32 b2 = ((u32)(u16)v[2]) << 16, b3 = ((u32)(u16)v[3]) << 16;
      u32 b4 = ((u32)(u16)v[4]) << 16, b5 = ((u32)(u16)v[5]) << 16;
      u32 b6 = ((u32)(u16)v[6]) << 16, b7 = ((u32)(u16)v[7]) << 16;
      a0 = fmaf(*reinterpret_cast<float*>(&b0), rc[g * 8 + 0], a0);
      a1 = fmaf(*reinterpret_cast<float*>(&b1), rc[g * 8 + 1], a1);
      a2 = fmaf(*reinterpret_cast<float*>(&b2), rc[g * 8 + 2], a2);
      a3 = fmaf(*reinterpret_cast<float*>(&b3), rc[g * 8 + 3], a3);
      a0 = fmaf(*reinterpret_cast<float*>(&b4), rc[g * 8 + 4], a0);
      a1 = fmaf(*reinterpret_cast<float*>(&b5), rc[g * 8 + 5], a1);
      a2 = fmaf(*reinterpret_cast<float*>(&b6), rc[g * 8 + 6], a2);
      a3 = fmaf(*reinterpret_cast<float*>(&b7), rc[g * 8 + 7], a3);
    }
    float s = (a0 + a1) + (a2 + a3);
    s += __shfl_xor(s, 1);
    s += __shfl_xor(s, 2);
    s += __shfl_xor(s, 4);
    s += __shfl_xor(s, 8);
    s += __shfl_xor(s, 16);
    s += __shfl_xor(s, 32);
    if (lane == 0) m.bfused[of] = s + m.out_b[of];
  }
}

// ---------------- attention g1 (transposed): S^T[k][q] = K·Q^T ----------------
// P stored in BLOCKED layout P[kt][q][128] (kt = k/128).
__global__ __launch_bounds__(256) void attn_g1_k(
    const u16* __restrict__ Qr, const u16* __restrict__ Kr,
    const u16* __restrict__ Qc, const u16* __restrict__ Kc,
    u16* __restrict__ Pr, u16* __restrict__ Pc, float* __restrict__ Lp,
    const float* __restrict__ am, const float* __restrict__ cmask,
    float sReg, float sCul, int zoff) {
  __shared__ __align__(16) u16 lA[128 * 64];
  __shared__ __align__(16) u16 lB[128 * 64];
  const int tid = threadIdx.x, w = tid >> 6, lane = tid & 63;
  const int quad = lane >> 4, l15 = lane & 15;
  const int m0 = blockIdx.y * 128, n0 = blockIdx.x * 128;  // m=key, n=query
  const int gz = zoff + blockIdx.z;
  const u16 *A, *BT;
  u16* P;
  const float* cm = nullptr;
  float scl;
  int K, b;
  if (gz < 12) {
    A = Kr + (size_t)gz * S_ * 128;
    BT = Qr + (size_t)gz * S_ * 128;
    K = 128;
    P = Pr + (size_t)blockIdx.z * (size_t)S_ * S_;
    scl = sReg;
    b = gz / 6;
  } else {
    int hc = gz - 12;
    A = Kc + (size_t)hc * S_ * 384;
    BT = Qc + (size_t)hc * S_ * 384;
    K = 384;
    P = Pc + (size_t)hc * (size_t)S_ * S_;
    b = hc >> 1;
    cm = cmask + (size_t)b * S_ * S_;
    scl = sCul;
  }

  const f32x4 z4 = {0.f, 0.f, 0.f, 0.f};
  f32x4 acc[4][4];
#pragma unroll
  for (int i = 0; i < 4; ++i)
#pragma unroll
    for (int j = 0; j < 4; ++j) acc[i][j] = z4;

  for (int kc = 0; kc < K; kc += 64) {
    stage64(A + (size_t)m0 * K + kc, K, lA, w, lane);
    stage64(BT + (size_t)n0 * K + kc, K, lB, w, lane);
    __syncthreads();
    mfma_chunk64(lA, lB, acc, w, l15, quad);
    __syncthreads();
  }

  // epilogue: p = exp2(acc*scl + am[k]*l2e (+ cm[q][k]*l2e) - M)
  // blocked P write: Pb[q][kb&127], dense per block.
  u16* Pb = P + (size_t)(m0 >> 7) * (S_ * 128);
  const float* amb = am + b * S_;
  float lsum[4] = {0.f, 0.f, 0.f, 0.f};
#pragma unroll
  for (int i = 0; i < 4; ++i) {
    int kb = m0 + (w >> 1) * 64 + i * 16 + quad * 4;    // 4 consecutive keys
    int kbl = kb & 127;
    float4 a4 = *reinterpret_cast<const float4*>(amb + kb);
    float pre0 = fmaf(a4.x, L2E_, -FML2_);
    float pre1 = fmaf(a4.y, L2E_, -FML2_);
    float pre2 = fmaf(a4.z, L2E_, -FML2_);
    float pre3 = fmaf(a4.w, L2E_, -FML2_);
#pragma unroll
    for (int j = 0; j < 4; ++j) {
      int q = n0 + (w & 1) * 64 + j * 16 + l15;
      float c0 = pre0, c1 = pre1, c2 = pre2, c3 = pre3;
      if (cm) {
        float4 cmv = *reinterpret_cast<const float4*>(cm + (size_t)q * S_ + kb);
        c0 = fmaf(cmv.x, L2E_, c0);
        c1 = fmaf(cmv.y, L2E_, c1);
        c2 = fmaf(cmv.z, L2E_, c2);
        c3 = fmaf(cmv.w, L2E_, c3);
      }
      float p0 = exp2f(fmaf(acc[i][j][0], scl, c0));
      float p1 = exp2f(fmaf(acc[i][j][1], scl, c1));
      float p2 = exp2f(fmaf(acc[i][j][2], scl, c2));
      float p3 = exp2f(fmaf(acc[i][j][3], scl, c3));
      lsum[j] += (p0 + p1) + (p2 + p3);
      *reinterpret_cast<uint2*>(Pb + (size_t)q * 128 + kbl) =
          make_uint2(pk2(p0, p1), pk2(p2, p3));
    }
  }
#pragma unroll
  for (int j = 0; j < 4; ++j) {
    float s = lsum[j];
    s += __shfl_xor(s, 16);
    s += __shfl_xor(s, 32);
    if (lane < 16)
      Lp[(size_t)gz * (32 * S_) + ((size_t)((m0 >> 7) * 2 + (w >> 1))) * S_ +
         n0 + (w & 1) * 64 + j * 16 + lane] = s;
  }
}

// ---------------- attention g2 (transposed): O^T[d][q] = Vt·P^T ----------------
// P read from blocked layout [kt][q][128]; double-buffered 2-phase pipeline.
__global__ __launch_bounds__(256) void attn_g2_k(
    const u16* __restrict__ Pr, const u16* __restrict__ Pc,
    const u16* __restrict__ Vtr, const u16* __restrict__ Vtc,
    const float* __restrict__ Lp, u16* __restrict__ AO, int zoff) {
  const int gz = zoff + blockIdx.z;
  const int m0 = blockIdx.y * 128, n0 = blockIdx.x * 128;  // m=feat, n=query
  const u16 *A, *BT;
  int b, colbase;
  if (gz < 12) {
    if (blockIdx.y) return;  // M = 128
    A = Vtr + (size_t)gz * 128 * S_;
    BT = Pr + (size_t)blockIdx.z * (size_t)S_ * S_;
    b = gz / 6;
    colbase = (gz % 6) * 128;
  } else {
    int hc = gz - 12;
    A = Vtc + (size_t)hc * 384 * S_;
    BT = Pc + (size_t)hc * (size_t)S_ * S_;
    b = hc >> 1;
    colbase = 768 + (hc & 1) * 384;
  }
  __shared__ __align__(16) u16 lA[2][128 * 64];
  __shared__ __align__(16) u16 lB[2][128 * 64];
  __shared__ float lL[128];
  const int tid = threadIdx.x, w = tid >> 6, lane = tid & 63;
  const int quad = lane >> 4, l15 = lane & 15;

  if (tid < 128) {
    const float* lp = Lp + (size_t)gz * (32 * S_) + (n0 + tid);
    float s = 0.f;
#pragma unroll
    for (int g = 0; g < 32; ++g) s += lp[(size_t)g * S_];
    lL[tid] = 1.f / s;
  }

  const f32x4 z4 = {0.f, 0.f, 0.f, 0.f};
  f32x4 acc[4][4];
#pragma unroll
  for (int i = 0; i < 4; ++i)
#pragma unroll
    for (int j = 0; j < 4; ++j) acc[i][j] = z4;

  // blocked-P source for chunk starting at kc
  auto psrc = [&](int kc) {
    return BT + (size_t)(kc >> 7) * (S_ * 128) + (kc & 64) + (size_t)n0 * 128;
  };

  stage64(A + (size_t)m0 * S_, S_, lA[0], w, lane);
  stage64(psrc(0), 128, lB[0], w, lane);
  __syncthreads();
  int cur = 0;
  for (int t = 0; t < 32; ++t) {
    if (t < 31) {
      int kn = (t + 1) * 64;
      stage64(A + (size_t)m0 * S_ + kn, S_, lA[cur ^ 1], w, lane);
      stage64(psrc(kn), 128, lB[cur ^ 1], w, lane);
    }
    mfma_chunk64(lA[cur], lB[cur], acc, w, l15, quad);
    __syncthreads();
    cur ^= 1;
  }

  float invl[4];
#pragma unroll
  for (int j = 0; j < 4; ++j) invl[j] = lL[(w & 1) * 64 + j * 16 + l15];
#pragma unroll
  for (int i = 0; i < 4; ++i) {
    int feat = colbase + m0 + (w >> 1) * 64 + i * 16 + quad * 4;
#pragma unroll
    for (int j = 0; j < 4; ++j) {
      int q = n0 + (w & 1) * 64 + j * 16 + l15;
      float v0 = acc[i][j][0] * invl[j];
      float v1 = acc[i][j][1] * invl[j];
      float v2 = acc[i][j][2] * invl[j];
      float v3 = acc[i][j][3] * invl[j];
      *reinterpret_cast<uint2*>(AO + ((size_t)(b * S_ + q)) * 1536 + feat) =
          make_uint2(pk2(v0, v1), pk2(v2, v3));
    }
  }
}

// ---------------- launcher ----------------

extern "C" void kernel_launch(void* const* d_in, const int* in_sizes, int n_in,
                              void* d_out, int out_size, void* d_ws, size_t ws_size,
                              hipStream_t stream) {
  const float* x     = (const float*)d_in[0];
  const float* cmask = (const float*)d_in[1];
  const float* amask = (const float*)d_in[2];
  const float* W[8]  = { (const float*)d_in[3], (const float*)d_in[4], (const float*)d_in[5],
                         (const float*)d_in[6], (const float*)d_in[7], (const float*)d_in[8],
                         (const float*)d_in[9], (const float*)d_in[10] };
  const float* rq_b = (const float*)d_in[11];
  const float* rk_b = (const float*)d_in[12];
  const float* rv_b = (const float*)d_in[13];
  const float* ro_b = (const float*)d_in[14];
  const float* cq_b = (const float*)d_in[15];
  const float* ck_b = (const float*)d_in[16];
  const float* cv_b = (const float*)d_in[17];
  const float* co_b = (const float*)d_in[18];
  const float* r_cb = (const float*)d_in[19];
  const float* c_cb = (const float*)d_in[20];
  const float* out_w = (const float*)d_in[21];
  const float* out_b = (const float*)d_in[22];

  char* p = (char*)d_ws;
  auto carve = [&](size_t bytes) -> void* {
    void* r = (void*)p;
    p += (bytes + 255) & ~(size_t)255;
    return r;
  };
  u16* Xb    = (u16*)carve((size_t)BS_ * E_ * 2);       // dead after QKV gemm
  u16* WqkvT = (u16*)carve((size_t)4608 * 768 * 2);     // dead after QKV gemm
  u16* outwT = (u16*)carve((size_t)768 * 1536 * 2);
  u16* Wrc   = (u16*)carve((size_t)1536 * 768 * 2);     // [ro_w;co_w] bf16 straight
  u16* WfT   = (u16*)carve((size_t)768 * 1536 * 2);     // fused proj weight
  float* bqkv   = (float*)carve(4608 * 4);
  float* bzero  = (float*)carve(1536 * 4);
  float* bfused = (float*)carve(768 * 4);
  u16* Qr  = (u16*)carve((size_t)B_ * 6 * S_ * 128 * 2);
  u16* Kr  = (u16*)carve((size_t)B_ * 6 * S_ * 128 * 2);
  u16* Vtr = (u16*)carve((size_t)B_ * 6 * S_ * 128 * 2);
  u16* Qc  = (u16*)carve((size_t)B_ * 2 * S_ * 384 * 2);
  u16* Kc  = (u16*)carve((size_t)B_ * 2 * S_ * 384 * 2);
  u16* Vtc = (u16*)carve((size_t)B_ * 2 * S_ * 384 * 2);
  u16* AO  = (u16*)carve((size_t)BS_ * 1536 * 2);

  // Lp aliases dead Xb region (4.2 MB <= 6.3 MB).
  float* Lp = (float*)Xb;
  u16* Pcul = (u16*)carve((size_t)4 * S_ * S_ * 2);     // 33.6 MB
  size_t used = (size_t)(p - (char*)d_ws);
  size_t rem = (ws_size > used) ? (ws_size - used) : 0;
  int RCH;                                              // regular heads per chunk
  if      (rem >= (size_t)12 * S_ * S_ * 2 + 4096) RCH = 12;
  else if (rem >= (size_t)4  * S_ * S_ * 2 + 4096) RCH = 4;
  else                                             RCH = 2;
  u16* Preg = (u16*)carve((size_t)RCH * S_ * S_ * 2);

  const float sReg = 0.08838834764831845f * L2E_;
  const float sCul = 0.05103103630798288f * L2E_;

  // ---- single preprocessing launch ----
  PrepP pp;
  pp.x = x; pp.Xb = Xb;
  pp.row = W[3]; pp.cow = W[7]; pp.Wrc = Wrc;
  const int wsel[6] = {0, 1, 2, 4, 5, 6};  // rq rk rv cq ck cv
  for (int i = 0; i < 6; ++i) {
    pp.tsrc[i] = W[wsel[i]];
    pp.tdst[i] = WqkvT + (size_t)i * 768 * 768;
    pp.trows[i] = 768;
  }
  pp.tsrc[6] = out_w; pp.tdst[6] = outwT; pp.trows[6] = 1536;
  pp.rqb = rq_b; pp.rkb = rk_b; pp.rvb = rv_b;
  pp.cqb = cq_b; pp.ckb = ck_b; pp.cvb = cv_b;
  pp.rcb = r_cb; pp.ccb = c_cb;
  pp.bqkv = bqkv; pp.bzero = bzero;
  prep_k<<<dim3(8856), 256, 0, stream>>>(pp);

  // ---- mega dispatch: QKV (1152) + WfT (72) + bfused (192) ----
  MegaP mp;
  mp.WqkvT = WqkvT; mp.Xb = Xb; mp.bqkv = bqkv;
  mp.Qr = Qr; mp.Kr = Kr; mp.Vtr = Vtr; mp.Qc = Qc; mp.Kc = Kc; mp.Vtc = Vtc;
  mp.Wrc = Wrc; mp.outwT = outwT; mp.bzero = bzero; mp.WfT = WfT;
  mp.out_b = out_b; mp.ro_b = ro_b; mp.co_b = co_b; mp.bfused = bfused;
  mega_k<<<dim3(1416), 256, 0, stream>>>(mp);

  if (RCH == 12) {
    attn_g1_k<<<dim3(16, 16, 16), 256, 0, stream>>>(
        Qr, Kr, Qc, Kc, Preg, Pcul, Lp, amask, cmask, sReg, sCul, 0);
    attn_g2_k<<<dim3(16, 3, 16), 256, 0, stream>>>(
        Preg, Pcul, Vtr, Vtc, Lp, AO, 0);
  } else {
    attn_g1_k<<<dim3(16, 16, 4), 256, 0, stream>>>(
        Qr, Kr, Qc, Kc, Preg, Pcul, Lp, amask, cmask, sReg, sCul, 12);
    attn_g2_k<<<dim3(16, 3, 4), 256, 0, stream>>>(
        Preg, Pcul, Vtr, Vtc, Lp, AO, 12);
    for (int c = 0; c < 12; c += RCH) {
      attn_g1_k<<<dim3(16, 16, RCH), 256, 0, stream>>>(
          Qr, Kr, Qc, Kc, Preg, Pcul, Lp, amask, cmask, sReg, sCul, c);
      attn_g2_k<<<dim3(16, 1, RCH), 256, 0, stream>>>(
          Preg, Pcul, Vtr, Vtc, Lp, AO, c);
    }
  }

  // final fused projection: M=768 out-features, N=4096 tokens, K=1536
  gemm_t_k<1, 1><<<dim3(32, 6), 256, 0, stream>>>(
      WfT, 1536, AO, 1536, bfused, 1536,
      (const u16*)nullptr, 0, 0, d_out, 768,
      nullptr, nullptr, nullptr, nullptr, nullptr, nullptr);
}